// Round 8
// baseline (84.812 us; speedup 1.0000x reference)
//
#include <hip/hip_runtime.h>

// TrigoLinear: out[b,o] = sum_i sin(x[b,i]*ws[o,i] + bs[o,i]) * wo[o,i] + b_out[o]
// B=1024, IN=512, OUT=512, fp32.
//
// R8 = R7 minus the combine kernel: GEMM does full K per block (no KSPLIT, no
// partials) and adds K[o] in the epilogue. 32x32 block tiles keep the grid at
// 512 blocks (2048 waves). Saves one kernel node + gap + 18 MB of round-trips.
//
// Math (unchanged): cubic Taylor (|u|=|x*ws|<=0.23) as polynomial in x =>
//   out[b,o] = sum_i A1*x + A2*x^2 + A3*x^3 + K[o],  K[o]=b_out+sum_i wo*sin(bs)
// fp16 GEMM Xf(1024x1536) x Wt^T(1536x512), fp32 acc; exact power-of-2 scaling.

#define B_DIM   1024
#define IN_DIM  512
#define OUT_DIM 512
#define KDIM    1536

// ws float offsets
#define XF_OFF  0          // _Float16[1024][1536] = 786432 floats
#define WT_OFF  786432     // _Float16[512][1536]  = 393216 floats
#define FC_OFF  1179648    // float[512] : K[o]

typedef _Float16 h8 __attribute__((ext_vector_type(8)));
typedef _Float16 h4 __attribute__((ext_vector_type(4)));
typedef float    f4v __attribute__((ext_vector_type(4)));

// ---- fused prep: blocks [0,512) build Wt row o + K[o]; [512,1024) build Xf ----
__global__ __launch_bounds__(256) void prep_kernel(
    const float* __restrict__ x, const float* __restrict__ weight,
    const float* __restrict__ bias, float* __restrict__ ws)
{
    _Float16* Xf = reinterpret_cast<_Float16*>(ws + XF_OFF);
    _Float16* Wt = reinterpret_cast<_Float16*>(ws + WT_OFF);
    const int t = threadIdx.x;

    if (blockIdx.x < 512) {
        const int o = blockIdx.x;
        _Float16* wrow = Wt + (size_t)o * KDIM;
        float c0sum = 0.f;
#pragma unroll
        for (int h = 0; h < 2; ++h) {
            int i = t + h * 256;
            float2 w = reinterpret_cast<const float2*>(weight)[(size_t)o * 512 + i]; // (wo, ws)
            float bs = bias[(size_t)o * 513 + i];
            float b2 = bs * bs;
            float sb = bs * fmaf(b2, -1.f / 6.f, 1.f);      // sin(bs), err ~1e-9
            float cb = fmaf(b2, -0.5f, 1.f);                 // cos(bs), err ~1.6e-7
            float c1 = w.x * cb;
            float c0 = w.x * sb;
            float wsn = w.y, ws2 = wsn * wsn;
            wrow[i]        = (_Float16)(16.f * c1 * wsn);            // 16*A1
            wrow[512 + i]  = (_Float16)(-128.f * c0 * ws2);          // 256*A2
            wrow[1024 + i] = (_Float16)((-256.f / 6.f) * c1 * wsn * ws2); // 256*A3
            c0sum += c0;
        }
        __shared__ float red[4];
#pragma unroll
        for (int off = 32; off; off >>= 1) c0sum += __shfl_down(c0sum, off, 64);
        if ((t & 63) == 0) red[t >> 6] = c0sum;
        __syncthreads();
        if (t == 0)
            (ws + FC_OFF)[o] = bias[(size_t)o * 513 + 512]
                               + red[0] + red[1] + red[2] + red[3];
    } else {
        // Xf[b][k]: [x/16 | x^2/256 | x^3/256]
        int idx = (blockIdx.x - 512) * 256 + t;        // [0, 131072)
        int b = idx >> 7, q = idx & 127;
        float4 v = reinterpret_cast<const float4*>(x)[idx];
        float xs[4] = {v.x, v.y, v.z, v.w};
        h4 p1, p2, p3;
#pragma unroll
        for (int c = 0; c < 4; ++c) {
            float xv = xs[c], xx = xv * xv;
            p1[c] = (_Float16)(xv * 0.0625f);
            p2[c] = (_Float16)(xx * (1.f / 256.f));
            p3[c] = (_Float16)(xv * xx * (1.f / 256.f));
        }
        _Float16* row = Xf + (size_t)b * KDIM + q * 4;
        *reinterpret_cast<h4*>(row)        = p1;
        *reinterpret_cast<h4*>(row + 512)  = p2;
        *reinterpret_cast<h4*>(row + 1024) = p3;
    }
}

// ---- GEMM + epilogue: out = Xf * Wt^T + K[o]; 32x32 tile, 4 waves (2x2 quads),
//      full K=1536 (48 MFMA/wave), fragments direct from L2 ----
__global__ __launch_bounds__(256) void gemm_kernel(const float* __restrict__ ws,
                                                   float* __restrict__ out)
{
    const _Float16* Xf = reinterpret_cast<const _Float16*>(ws + XF_OFF);
    const _Float16* Wt = reinterpret_cast<const _Float16*>(ws + WT_OFF);
    const float*    Kc = ws + FC_OFF;

    const int w  = threadIdx.x >> 6;          // wave 0..3 -> 16x16 quadrant
    const int l  = threadIdx.x & 63;
    const int lr = l & 15, lq = l >> 4;       // lane row / k-quad
    const int m0 = blockIdx.x * 32 + (w & 1) * 16;   // b
    const int n0 = blockIdx.y * 32 + (w >> 1) * 16;  // o

    // A-frag: A[m = lane&15][k = (lane>>4)*8 + j]  (m89/m91-verified mapping)
    const _Float16* aP = Xf + (size_t)(m0 + lr) * KDIM + lq * 8;
    const _Float16* bP = Wt + (size_t)(n0 + lr) * KDIM + lq * 8;

    f4v acc = {0.f, 0.f, 0.f, 0.f};
#pragma unroll
    for (int it = 0; it < KDIM / 32; ++it) {   // 48 iters, imm offsets 0..3008B
        h8 a = *reinterpret_cast<const h8*>(aP + it * 32);
        h8 b = *reinterpret_cast<const h8*>(bP + it * 32);
        acc = __builtin_amdgcn_mfma_f32_16x16x32_f16(a, b, acc, 0, 0, 0);
    }

    // C/D: col = lane&15 (N=o), row = (lane>>4)*4 + reg (M=b)  (m89-verified)
    const int mB = m0 + lq * 4;
    const int nB = n0 + lr;
    const float k = Kc[nB];
#pragma unroll
    for (int r = 0; r < 4; ++r)
        out[(size_t)(mB + r) * OUT_DIM + nB] = acc[r] + k;
}

extern "C" void kernel_launch(void* const* d_in, const int* in_sizes, int n_in,
                              void* d_out, int out_size, void* d_ws, size_t ws_size,
                              hipStream_t stream) {
    const float* x      = (const float*)d_in[0];
    const float* weight = (const float*)d_in[1];
    const float* bias   = (const float*)d_in[2];
    float* out          = (float*)d_out;
    float* ws           = (float*)d_ws;

    prep_kernel<<<dim3(1024), dim3(256), 0, stream>>>(x, weight, bias, ws);
    // x-fastest: 32 consecutive blocks share one 96 KB Wt slice in L2
    gemm_kernel<<<dim3(B_DIM / 32, OUT_DIM / 32), dim3(256), 0, stream>>>(ws, out);
}

// Round 9
// 84.642 us; speedup vs baseline: 1.0020x; 1.0020x over previous
//
#include <hip/hip_runtime.h>

// TrigoLinear: out[b,o] = sum_i sin(x[b,i]*ws[o,i] + bs[o,i]) * wo[o,i] + b_out[o]
// B=1024, IN=512, OUT=512, fp32.
//
// R9 = R8 with the GEMM K-loop split into 4 interleaved accumulator chains.
// R8's single 48-deep dependent MFMA chain (2 waves/SIMD, 2KB fresh L2 data per
// MFMA) was latency-bound; 4 chains x 12 deep restores R7's per-wave ILP while
// keeping the fused epilogue (no KSPLIT partials, no combine kernel).
//
// Math (unchanged): cubic Taylor (|u|=|x*ws|<=0.23) as polynomial in x =>
//   out[b,o] = sum_i A1*x + A2*x^2 + A3*x^3 + K[o],  K[o]=b_out+sum_i wo*sin(bs)
// fp16 GEMM Xf(1024x1536) x Wt^T(1536x512), fp32 acc; exact power-of-2 scaling.

#define B_DIM   1024
#define IN_DIM  512
#define OUT_DIM 512
#define KDIM    1536

// ws float offsets
#define XF_OFF  0          // _Float16[1024][1536] = 786432 floats
#define WT_OFF  786432     // _Float16[512][1536]  = 393216 floats
#define FC_OFF  1179648    // float[512] : K[o]

typedef _Float16 h8 __attribute__((ext_vector_type(8)));
typedef _Float16 h4 __attribute__((ext_vector_type(4)));
typedef float    f4v __attribute__((ext_vector_type(4)));

// ---- fused prep: blocks [0,512) build Wt row o + K[o]; [512,1024) build Xf ----
__global__ __launch_bounds__(256) void prep_kernel(
    const float* __restrict__ x, const float* __restrict__ weight,
    const float* __restrict__ bias, float* __restrict__ ws)
{
    _Float16* Xf = reinterpret_cast<_Float16*>(ws + XF_OFF);
    _Float16* Wt = reinterpret_cast<_Float16*>(ws + WT_OFF);
    const int t = threadIdx.x;

    if (blockIdx.x < 512) {
        const int o = blockIdx.x;
        _Float16* wrow = Wt + (size_t)o * KDIM;
        float c0sum = 0.f;
#pragma unroll
        for (int h = 0; h < 2; ++h) {
            int i = t + h * 256;
            float2 w = reinterpret_cast<const float2*>(weight)[(size_t)o * 512 + i]; // (wo, ws)
            float bs = bias[(size_t)o * 513 + i];
            float b2 = bs * bs;
            float sb = bs * fmaf(b2, -1.f / 6.f, 1.f);      // sin(bs), err ~1e-9
            float cb = fmaf(b2, -0.5f, 1.f);                 // cos(bs), err ~1.6e-7
            float c1 = w.x * cb;
            float c0 = w.x * sb;
            float wsn = w.y, ws2 = wsn * wsn;
            wrow[i]        = (_Float16)(16.f * c1 * wsn);            // 16*A1
            wrow[512 + i]  = (_Float16)(-128.f * c0 * ws2);          // 256*A2
            wrow[1024 + i] = (_Float16)((-256.f / 6.f) * c1 * wsn * ws2); // 256*A3
            c0sum += c0;
        }
        __shared__ float red[4];
#pragma unroll
        for (int off = 32; off; off >>= 1) c0sum += __shfl_down(c0sum, off, 64);
        if ((t & 63) == 0) red[t >> 6] = c0sum;
        __syncthreads();
        if (t == 0)
            (ws + FC_OFF)[o] = bias[(size_t)o * 513 + 512]
                               + red[0] + red[1] + red[2] + red[3];
    } else {
        // Xf[b][k]: [x/16 | x^2/256 | x^3/256]
        int idx = (blockIdx.x - 512) * 256 + t;        // [0, 131072)
        int b = idx >> 7, q = idx & 127;
        float4 v = reinterpret_cast<const float4*>(x)[idx];
        float xs[4] = {v.x, v.y, v.z, v.w};
        h4 p1, p2, p3;
#pragma unroll
        for (int c = 0; c < 4; ++c) {
            float xv = xs[c], xx = xv * xv;
            p1[c] = (_Float16)(xv * 0.0625f);
            p2[c] = (_Float16)(xx * (1.f / 256.f));
            p3[c] = (_Float16)(xv * xx * (1.f / 256.f));
        }
        _Float16* row = Xf + (size_t)b * KDIM + q * 4;
        *reinterpret_cast<h4*>(row)        = p1;
        *reinterpret_cast<h4*>(row + 512)  = p2;
        *reinterpret_cast<h4*>(row + 1024) = p3;
    }
}

// ---- GEMM + epilogue: out = Xf * Wt^T + K[o]; 32x32 block tile, 4 waves,
//      full K=1536 as 4 interleaved chains x 12 MFMA, fragments direct from L2 ----
__global__ __launch_bounds__(256) void gemm_kernel(const float* __restrict__ ws,
                                                   float* __restrict__ out)
{
    const _Float16* Xf = reinterpret_cast<const _Float16*>(ws + XF_OFF);
    const _Float16* Wt = reinterpret_cast<const _Float16*>(ws + WT_OFF);
    const float*    Kc = ws + FC_OFF;

    const int w  = threadIdx.x >> 6;          // wave 0..3 -> 16x16 quadrant
    const int l  = threadIdx.x & 63;
    const int lr = l & 15, lq = l >> 4;       // lane row / k-quad
    const int m0 = blockIdx.x * 32 + (w & 1) * 16;   // b
    const int n0 = blockIdx.y * 32 + (w >> 1) * 16;  // o

    // A-frag: A[m = lane&15][k = (lane>>4)*8 + j]  (m89/m91-verified mapping)
    const _Float16* aP = Xf + (size_t)(m0 + lr) * KDIM + lq * 8;
    const _Float16* bP = Wt + (size_t)(n0 + lr) * KDIM + lq * 8;

    f4v acc0 = {0.f, 0.f, 0.f, 0.f};
    f4v acc1 = acc0, acc2 = acc0, acc3 = acc0;

#pragma unroll
    for (int it = 0; it < KDIM / 128; ++it) {  // 12 outer iters, 4 chains each
        h8 a0 = *reinterpret_cast<const h8*>(aP + (4 * it + 0) * 32);
        h8 b0 = *reinterpret_cast<const h8*>(bP + (4 * it + 0) * 32);
        h8 a1 = *reinterpret_cast<const h8*>(aP + (4 * it + 1) * 32);
        h8 b1 = *reinterpret_cast<const h8*>(bP + (4 * it + 1) * 32);
        h8 a2 = *reinterpret_cast<const h8*>(aP + (4 * it + 2) * 32);
        h8 b2 = *reinterpret_cast<const h8*>(bP + (4 * it + 2) * 32);
        h8 a3 = *reinterpret_cast<const h8*>(aP + (4 * it + 3) * 32);
        h8 b3 = *reinterpret_cast<const h8*>(bP + (4 * it + 3) * 32);
        acc0 = __builtin_amdgcn_mfma_f32_16x16x32_f16(a0, b0, acc0, 0, 0, 0);
        acc1 = __builtin_amdgcn_mfma_f32_16x16x32_f16(a1, b1, acc1, 0, 0, 0);
        acc2 = __builtin_amdgcn_mfma_f32_16x16x32_f16(a2, b2, acc2, 0, 0, 0);
        acc3 = __builtin_amdgcn_mfma_f32_16x16x32_f16(a3, b3, acc3, 0, 0, 0);
    }

    f4v acc = (acc0 + acc1) + (acc2 + acc3);   // fp32, exact reassociation-safe

    // C/D: col = lane&15 (N=o), row = (lane>>4)*4 + reg (M=b)  (m89-verified)
    const int mB = m0 + lq * 4;
    const int nB = n0 + lr;
    const float k = Kc[nB];
#pragma unroll
    for (int r = 0; r < 4; ++r)
        out[(size_t)(mB + r) * OUT_DIM + nB] = acc[r] + k;
}

extern "C" void kernel_launch(void* const* d_in, const int* in_sizes, int n_in,
                              void* d_out, int out_size, void* d_ws, size_t ws_size,
                              hipStream_t stream) {
    const float* x      = (const float*)d_in[0];
    const float* weight = (const float*)d_in[1];
    const float* bias   = (const float*)d_in[2];
    float* out          = (float*)d_out;
    float* ws           = (float*)d_ws;

    prep_kernel<<<dim3(1024), dim3(256), 0, stream>>>(x, weight, bias, ws);
    // x-fastest: 32 consecutive blocks share one 96 KB Wt slice in L2
    gemm_kernel<<<dim3(B_DIM / 32, OUT_DIM / 32), dim3(256), 0, stream>>>(ws, out);
}

// Round 10
// 78.106 us; speedup vs baseline: 1.0859x; 1.0837x over previous
//
#include <hip/hip_runtime.h>

// TrigoLinear: out[b,o] = sum_i sin(x[b,i]*ws[o,i] + bs[o,i]) * wo[o,i] + b_out[o]
// B=1024, IN=512, OUT=512, fp32.
//
// R10 = exact revert to R7 (the measured best, 78.7 us). R8/R9's fused-epilogue
// GEMMs had 1x1 register blocking -> 2 KB fragments/MFMA vs R7's 2x2 blocking
// at 1 KB/MFMA; load-path bound, +6 us. R7's KSPLIT=4 + 64x64 block tile is the
// balanced point: 2048 waves (8/CU) AND 2x fragment reuse.
//
// Math: cubic Taylor (|u|=|x*ws|<=0.23) as polynomial in x =>
//   out[b,o] = sum_i A1*x + A2*x^2 + A3*x^3 + K[o]
//   A1=wo*cos(bs)*ws, A2=-wo*sin(bs)/2*ws^2, A3=-wo*cos(bs)/6*ws^3,
//   K[o]=b_out[o]+sum_i wo*sin(bs).
// fp16 GEMM Xf(1024x1536) x Wt^T(1536x512), fp32 acc; exact power-of-2 scaling.

#define B_DIM   1024
#define IN_DIM  512
#define OUT_DIM 512
#define KDIM    1536
#define KSPLIT  4
#define KC      (KDIM / KSPLIT)   // 384

// ws float offsets
#define XF_OFF  0          // _Float16[1024][1536] = 786432 floats
#define WT_OFF  786432     // _Float16[512][1536]  = 393216 floats
#define FC_OFF  1179648    // float[512] : K[o]
#define PT_OFF  1180160    // float[4][1024][512] = 2097152 floats

typedef _Float16 h8 __attribute__((ext_vector_type(8)));
typedef _Float16 h4 __attribute__((ext_vector_type(4)));
typedef float    f4v __attribute__((ext_vector_type(4)));

// ---- fused prep: blocks [0,512) build Wt row o + K[o]; [512,1024) build Xf ----
__global__ __launch_bounds__(256) void prep_kernel(
    const float* __restrict__ x, const float* __restrict__ weight,
    const float* __restrict__ bias, float* __restrict__ ws)
{
    _Float16* Xf = reinterpret_cast<_Float16*>(ws + XF_OFF);
    _Float16* Wt = reinterpret_cast<_Float16*>(ws + WT_OFF);
    const int t = threadIdx.x;

    if (blockIdx.x < 512) {
        const int o = blockIdx.x;
        _Float16* wrow = Wt + (size_t)o * KDIM;
        float c0sum = 0.f;
#pragma unroll
        for (int h = 0; h < 2; ++h) {
            int i = t + h * 256;
            float2 w = reinterpret_cast<const float2*>(weight)[(size_t)o * 512 + i]; // (wo, ws)
            float bs = bias[(size_t)o * 513 + i];
            float b2 = bs * bs;
            float sb = bs * fmaf(b2, -1.f / 6.f, 1.f);      // sin(bs), err ~1e-9
            float cb = fmaf(b2, -0.5f, 1.f);                 // cos(bs), err ~1.6e-7
            float c1 = w.x * cb;
            float c0 = w.x * sb;
            float wsn = w.y, ws2 = wsn * wsn;
            wrow[i]        = (_Float16)(16.f * c1 * wsn);            // 16*A1
            wrow[512 + i]  = (_Float16)(-128.f * c0 * ws2);          // 256*A2
            wrow[1024 + i] = (_Float16)((-256.f / 6.f) * c1 * wsn * ws2); // 256*A3
            c0sum += c0;
        }
        __shared__ float red[4];
#pragma unroll
        for (int off = 32; off; off >>= 1) c0sum += __shfl_down(c0sum, off, 64);
        if ((t & 63) == 0) red[t >> 6] = c0sum;
        __syncthreads();
        if (t == 0)
            (ws + FC_OFF)[o] = bias[(size_t)o * 513 + 512]
                               + red[0] + red[1] + red[2] + red[3];
    } else {
        // Xf[b][k]: [x/16 | x^2/256 | x^3/256]
        int idx = (blockIdx.x - 512) * 256 + t;        // [0, 131072)
        int b = idx >> 7, q = idx & 127;
        float4 v = reinterpret_cast<const float4*>(x)[idx];
        float xs[4] = {v.x, v.y, v.z, v.w};
        h4 p1, p2, p3;
#pragma unroll
        for (int c = 0; c < 4; ++c) {
            float xv = xs[c], xx = xv * xv;
            p1[c] = (_Float16)(xv * 0.0625f);
            p2[c] = (_Float16)(xx * (1.f / 256.f));
            p3[c] = (_Float16)(xv * xx * (1.f / 256.f));
        }
        _Float16* row = Xf + (size_t)b * KDIM + q * 4;
        *reinterpret_cast<h4*>(row)        = p1;
        *reinterpret_cast<h4*>(row + 512)  = p2;
        *reinterpret_cast<h4*>(row + 1024) = p3;
    }
}

// ---- GEMM: part[z] = Xf(1024 x KC) * Wt^T slice; 64x64 block tile, 4 waves 2x2 ----
__global__ __launch_bounds__(256) void gemm_kernel(const float* __restrict__ ws,
                                                   float* __restrict__ part_out)
{
    const _Float16* Xf = reinterpret_cast<const _Float16*>(ws + XF_OFF);
    const _Float16* Wt = reinterpret_cast<const _Float16*>(ws + WT_OFF);

    const int w  = threadIdx.x >> 6;          // wave 0..3 -> 2x2 quadrants
    const int l  = threadIdx.x & 63;
    const int lr = l & 15, lq = l >> 4;       // lane row / k-quad
    const int m0 = blockIdx.x * 64 + (w & 1) * 32;
    const int n0 = blockIdx.y * 64 + (w >> 1) * 32;
    const int kz = blockIdx.z * KC;

    // A-frag: A[m = lane&15][k = (lane>>4)*8 + j]  (m89/m91-verified mapping)
    const _Float16* aP = Xf + (size_t)(m0 + lr) * KDIM + kz + lq * 8;
    const _Float16* bP = Wt + (size_t)(n0 + lr) * KDIM + kz + lq * 8;

    f4v acc00 = {0.f, 0.f, 0.f, 0.f};
    f4v acc01 = acc00, acc10 = acc00, acc11 = acc00;

#pragma unroll
    for (int it = 0; it < KC / 32; ++it) {     // 12 iters
        h8 a0 = *reinterpret_cast<const h8*>(aP + it * 32);
        h8 a1 = *reinterpret_cast<const h8*>(aP + 16 * KDIM + it * 32);
        h8 b0 = *reinterpret_cast<const h8*>(bP + it * 32);
        h8 b1 = *reinterpret_cast<const h8*>(bP + 16 * KDIM + it * 32);
        acc00 = __builtin_amdgcn_mfma_f32_16x16x32_f16(a0, b0, acc00, 0, 0, 0);
        acc01 = __builtin_amdgcn_mfma_f32_16x16x32_f16(a0, b1, acc01, 0, 0, 0);
        acc10 = __builtin_amdgcn_mfma_f32_16x16x32_f16(a1, b0, acc10, 0, 0, 0);
        acc11 = __builtin_amdgcn_mfma_f32_16x16x32_f16(a1, b1, acc11, 0, 0, 0);
    }

    // C/D: col = lane&15 (N), row = (lane>>4)*4 + reg (M)  (m89-verified)
    float* base = part_out + (size_t)blockIdx.z * B_DIM * OUT_DIM;
    const int mB = m0 + lq * 4;
    const int nB = n0 + lr;
#pragma unroll
    for (int r = 0; r < 4; ++r) {
        base[(size_t)(mB + r) * OUT_DIM + nB]           = acc00[r];
        base[(size_t)(mB + r) * OUT_DIM + nB + 16]      = acc01[r];
        base[(size_t)(mB + 16 + r) * OUT_DIM + nB]      = acc10[r];
        base[(size_t)(mB + 16 + r) * OUT_DIM + nB + 16] = acc11[r];
    }
}

// ---- combine: out = sum_z part[z] + K[o] ----
__global__ __launch_bounds__(256) void combine_kernel(
    const float* __restrict__ ws, float* __restrict__ out)
{
    int t = blockIdx.x * 256 + threadIdx.x;    // float4 index, [0, 131072)
    const float4* p4 = reinterpret_cast<const float4*>(ws + PT_OFF);
    float4 s = reinterpret_cast<const float4*>(ws + FC_OFF)[t & 127];
#pragma unroll
    for (int z = 0; z < KSPLIT; ++z) {
        float4 q = p4[(size_t)z * 131072 + t];
        s.x += q.x; s.y += q.y; s.z += q.z; s.w += q.w;
    }
    reinterpret_cast<float4*>(out)[t] = s;
}

extern "C" void kernel_launch(void* const* d_in, const int* in_sizes, int n_in,
                              void* d_out, int out_size, void* d_ws, size_t ws_size,
                              hipStream_t stream) {
    const float* x      = (const float*)d_in[0];
    const float* weight = (const float*)d_in[1];
    const float* bias   = (const float*)d_in[2];
    float* out          = (float*)d_out;
    float* ws           = (float*)d_ws;

    prep_kernel<<<dim3(1024), dim3(256), 0, stream>>>(x, weight, bias, ws);
    gemm_kernel<<<dim3(B_DIM / 64, OUT_DIM / 64, KSPLIT), dim3(256), 0, stream>>>(
        ws, ws + PT_OFF);
    combine_kernel<<<dim3((B_DIM * OUT_DIM / 4) / 256), dim3(256), 0, stream>>>(ws, out);
}